// Round 5
// baseline (140.296 us; speedup 1.0000x reference)
//
#include <hip/hip_runtime.h>
#include <cstddef>

#define NN 512
#define NEG_SLOPE 0.2f

typedef __attribute__((ext_vector_type(8))) short short8;
typedef __attribute__((ext_vector_type(16))) float f32x16;

__device__ __forceinline__ unsigned short f2bf(float v) {
  unsigned u = __float_as_uint(v);
  return (unsigned short)((u + 0x7FFFu + ((u >> 16) & 1u)) >> 16);
}

// ---------------- K1: fused mask-build + gemm1.
// Block (b,mt), 256 threads. Waves 1..3 build the mask tile (d in [mt*32,+32), all 512 s)
// from adj. Wave 0 loads W1 fragments from L2, packs x, runs 32 MFMAs, bounces each
// 32x32 h1 tile through LDS to emit hb1 B-frags + fp32 e1 dots.
__global__ __launch_bounds__(256) void k_g1m(const int* __restrict__ adj,
                                             const float* __restrict__ x,
                                             const float* __restrict__ W1,
                                             const float* __restrict__ a1s,
                                             const float* __restrict__ a1d,
                                             unsigned* __restrict__ mask,
                                             unsigned short* __restrict__ hb1,
                                             float* __restrict__ e1s,
                                             float* __restrict__ e1d) {
  __shared__ float tile[32 * 36];  // stride 36: 16B-aligned rows for e-dot b128
  int i = blockIdx.x;
  int b = (i & 7) * 4 + ((i >> 3) & 3), mt = i >> 5;  // XCD-affine swizzle
  int d0 = mt * 32;
  int t = threadIdx.x;

  if (t >= 64) {
    // mask helper: 192 threads cover 512 (w,d) words; word u: d=u&31, w=u>>5
    int t2 = t - 64;
    const int* abase = adj + (size_t)b * NN * NN;
    for (int u = t2; u < 512; u += 192) {
      int d = d0 + (u & 31), w = u >> 5;
      unsigned wv = 0;
#pragma unroll
      for (int j = 0; j < 32; ++j) {
        int s = w * 32 + j;
        unsigned bit = ((abase[(size_t)s * NN + d] != 0) || (s == d)) ? 1u : 0u;
        wv |= bit << j;
      }
      mask[((size_t)b * 16 + w) * NN + d] = wv;
    }
    return;  // no barriers in this kernel
  }

  // ---- wave 0: gemm1
  int lane = t, m = lane & 31, kg = lane >> 5;
  const float* xrow = x + ((size_t)b * NN + d0 + m) * 64 + kg * 8;
  short8 a[4];
#pragma unroll
  for (int kt = 0; kt < 4; ++kt) {
    float4 v0 = *(const float4*)(xrow + kt * 16);
    float4 v1 = *(const float4*)(xrow + kt * 16 + 4);
    short8 r;
    r[0] = (short)f2bf(v0.x); r[1] = (short)f2bf(v0.y);
    r[2] = (short)f2bf(v0.z); r[3] = (short)f2bf(v0.w);
    r[4] = (short)f2bf(v1.x); r[5] = (short)f2bf(v1.y);
    r[6] = (short)f2bf(v1.z); r[7] = (short)f2bf(v1.w);
    a[kt] = r;
  }
  short8* hb8 = (short8*)hb1;
  // double-buffered W1 fragment registers
  short8 wf[2][4];
#pragma unroll
  for (int kt = 0; kt < 4; ++kt) {
    int k0 = kt * 16 + kg * 8;
    short8 r;
#pragma unroll
    for (int j = 0; j < 8; ++j) r[j] = (short)f2bf(W1[(k0 + j) * 256 + m]);
    wf[0][kt] = r;
  }
  float e_h = 0.f;
#pragma unroll
  for (int nt = 0; nt < 8; ++nt) {
    int cur = nt & 1;
    if (nt < 7) {
      int f = (nt + 1) * 32 + m;
#pragma unroll
      for (int kt = 0; kt < 4; ++kt) {
        int k0 = kt * 16 + kg * 8;
        short8 r;
#pragma unroll
        for (int j = 0; j < 8; ++j) r[j] = (short)f2bf(W1[(k0 + j) * 256 + f]);
        wf[cur ^ 1][kt] = r;
      }
    }
    f32x16 acc;
#pragma unroll
    for (int q = 0; q < 16; ++q) acc[q] = 0.f;
#pragma unroll
    for (int kt = 0; kt < 4; ++kt)
      acc = __builtin_amdgcn_mfma_f32_32x32x16_bf16(a[kt], wf[cur][kt], acc, 0, 0, 0);
#pragma unroll
    for (int reg = 0; reg < 16; ++reg) {
      int row = (reg & 3) + 8 * (reg >> 2) + 4 * kg;  // C/D row map (m74/m101)
      tile[row * 36 + m] = acc[reg];
    }
    // hb1 B-frag pack (intra-wave LDS RAW: compiler orders via lgkmcnt)
    int h = nt >> 1, ft = nt & 1;
#pragma unroll
    for (int ktl = 0; ktl < 2; ++ktl) {
      short8 r;
#pragma unroll
      for (int j = 0; j < 8; ++j)
        r[j] = (short)f2bf(tile[(ktl * 16 + kg * 8 + j) * 36 + m]);
      hb8[((((size_t)b * 4 + h) * 32 + mt * 2 + ktl) * 2 + ft) * 64 + lane] = r;
    }
    // fp32 e-dot on the tile: lane (row=m, which=kg)
    const float* coeff = (kg ? a1d : a1s) + h * 64 + ft * 32;
    float ep = 0.f;
#pragma unroll
    for (int c4 = 0; c4 < 8; ++c4) {
      float4 tv = *(const float4*)&tile[m * 36 + c4 * 4];
      float4 cv = *(const float4*)&coeff[c4 * 4];
      ep += tv.x * cv.x + tv.y * cv.y + tv.z * cv.z + tv.w * cv.w;
    }
    e_h += ep;
    if (ft) {
      float* p = kg ? e1d : e1s;
      p[((size_t)b * 4 + h) * NN + d0 + m] = e_h;
      e_h = 0.f;
    }
  }
}

// ---------------- K2: fused layer-1 attention + layer-2 GEMM (+e2 dots).
__global__ __launch_bounds__(256) void k_attn1g2(const unsigned* __restrict__ mask,
                                                 const unsigned short* __restrict__ hb1,
                                                 const float* __restrict__ e1s,
                                                 const float* __restrict__ e1d,
                                                 const float* __restrict__ b1,
                                                 const float* __restrict__ W2,
                                                 const float* __restrict__ a2s,
                                                 const float* __restrict__ a2d,
                                                 unsigned short* __restrict__ hb2,
                                                 float* __restrict__ e2s,
                                                 float* __restrict__ e2d) {
  __shared__ float es[4 * NN];             // 8 KB
  __shared__ unsigned mw[16 * 32];         // 2 KB
  __shared__ unsigned short ht[32 * 264];  // 16.5 KB
  __shared__ float tile2[2][32 * 36];      // 9.2 KB
  int i = blockIdx.x;
  int b = (i & 7) * 4 + ((i >> 3) & 3), mt = i >> 5;  // XCD-affine swizzle
  int d0 = mt * 32;
  int t = threadIdx.x;
  const float* esrc = e1s + (size_t)b * 4 * NN;
#pragma unroll
  for (int q = 0; q < 8; ++q) es[t + q * 256] = esrc[t + q * 256];
  const unsigned* msrc = mask + (size_t)b * 16 * NN + d0;
  mw[t] = msrc[(t >> 5) * NN + (t & 31)];
  {
    int idx = t + 256;
    mw[idx] = msrc[(idx >> 5) * NN + (idx & 31)];
  }
  __syncthreads();
  int h = t >> 6, lane = t & 63, m = lane & 31, kg = lane >> 5;
  float ed = e1d[((size_t)b * 4 + h) * NN + d0 + m];
  const short8* bfr = (const short8*)hb1 + ((size_t)b * 4 + h) * 32 * 2 * 64;
  f32x16 acc0, acc1;
#pragma unroll
  for (int q = 0; q < 16; ++q) { acc0[q] = 0.f; acc1[q] = 0.f; }
  float l = 0.f;
  for (int kt = 0; kt < 32; ++kt) {
    unsigned wv = mw[(kt >> 1) * 32 + m];
    int shift = (kt & 1) * 16 + kg * 8;
    const float* ep = &es[h * NN + kt * 16 + kg * 8];
    short8 a;
#pragma unroll
    for (int j = 0; j < 8; ++j) {
      float sc = ed + ep[j];
      sc = fmaxf(sc, NEG_SLOPE * sc);  // leaky_relu
      float pv = __expf(sc);           // scores O(+-8): no max-shift needed
      pv = ((wv >> (shift + j)) & 1u) ? pv : 0.f;
      l += pv;
      a[j] = (short)f2bf(pv);
    }
    short8 bv0 = bfr[(kt * 2 + 0) * 64 + lane];
    short8 bv1 = bfr[(kt * 2 + 1) * 64 + lane];
    acc0 = __builtin_amdgcn_mfma_f32_32x32x16_bf16(a, bv0, acc0, 0, 0, 0);
    acc1 = __builtin_amdgcn_mfma_f32_32x32x16_bf16(a, bv1, acc1, 0, 0, 0);
  }
  float lf = l + __shfl(l, lane ^ 32, 64);
  float linv = 1.f / lf;
  float bia0 = b1[h * 64 + m];
  float bia1 = b1[h * 64 + 32 + m];
#pragma unroll
  for (int reg = 0; reg < 16; ++reg) {
    int row = (reg & 3) + 8 * (reg >> 2) + 4 * kg;  // C/D row map
    float li = __shfl(linv, row, 64);
    float v0 = acc0[reg] * li + bia0;
    v0 = (v0 > 0.f) ? v0 : (__expf(v0) - 1.f);  // ELU
    float v1 = acc1[reg] * li + bia1;
    v1 = (v1 > 0.f) ? v1 : (__expf(v1) - 1.f);
    ht[row * 264 + h * 64 + m] = f2bf(v0);
    ht[row * 264 + h * 64 + 32 + m] = f2bf(v1);
  }
  __syncthreads();
  // ---- fused gemm2: waves 0/1 compute n-tile nt=w2 of h1a@W2 from ht
  int w2 = t >> 6;
  if (w2 < 2) {
    int nt = w2;
    short8 wfr[16];
#pragma unroll
    for (int kt = 0; kt < 16; ++kt) {
      int k0 = kt * 16 + kg * 8;
      short8 r;
#pragma unroll
      for (int j = 0; j < 8; ++j)
        r[j] = (short)f2bf(W2[(k0 + j) * 64 + nt * 32 + m]);
      wfr[kt] = r;
    }
    f32x16 acc;
#pragma unroll
    for (int q = 0; q < 16; ++q) acc[q] = 0.f;
#pragma unroll
    for (int kt = 0; kt < 16; ++kt) {
      short8 av = *(const short8*)&ht[m * 264 + kt * 16 + kg * 8];
      acc = __builtin_amdgcn_mfma_f32_32x32x16_bf16(av, wfr[kt], acc, 0, 0, 0);
    }
    float* tw = tile2[nt];
#pragma unroll
    for (int reg = 0; reg < 16; ++reg) {
      int row = (reg & 3) + 8 * (reg >> 2) + 4 * kg;
      tw[row * 36 + m] = acc[reg];
    }
  }
  __syncthreads();
  if (w2 < 2) {
    // pack hb2 B-frags
    const float* tw = tile2[w2];
    short8* hb8 = (short8*)hb2;
#pragma unroll
    for (int ktl = 0; ktl < 2; ++ktl) {
      short8 r;
#pragma unroll
      for (int j = 0; j < 8; ++j)
        r[j] = (short)f2bf(tw[(ktl * 16 + kg * 8 + j) * 36 + m]);
      hb8[(((size_t)b * 32 + mt * 2 + ktl) * 2 + w2) * 64 + lane] = r;
    }
  } else {
    // waves 2/3: e2 dots. wave2 -> e2s, wave3 -> e2d
    const float* coeff = ((w2 == 2) ? a2s : a2d) + kg * 32;
    const float* tsrc = tile2[kg];
    float val = 0.f;
#pragma unroll
    for (int c4 = 0; c4 < 8; ++c4) {
      float4 tv = *(const float4*)&tsrc[m * 36 + c4 * 4];
      float4 cv = *(const float4*)&coeff[c4 * 4];
      val += tv.x * cv.x + tv.y * cv.y + tv.z * cv.z + tv.w * cv.w;
    }
    float tot = val + __shfl(val, lane ^ 32, 64);
    if (kg == 0) {
      float* p = (w2 == 2) ? e2s : e2d;
      p[(size_t)b * NN + d0 + m] = tot;
    }
  }
}

// ---------------- K3: layer-2 attention via MFMA, 4 waves split K, LDS reduce
__global__ __launch_bounds__(256) void k_attn2(const unsigned* __restrict__ mask,
                                               const unsigned short* __restrict__ hb2,
                                               const float* __restrict__ e2s,
                                               const float* __restrict__ e2d,
                                               const float* __restrict__ b2,
                                               float* __restrict__ out) {
  __shared__ float es[NN];
  __shared__ unsigned mw[16 * 32];
  __shared__ float cred[4][2][16][64];
  __shared__ float lred[4][64];
  __shared__ float linv_s[32];
  int i = blockIdx.x;
  int b = (i & 7) * 4 + ((i >> 3) & 3);  // XCD-affine swizzle
  int d0 = (i >> 5) * 32;
  int t = threadIdx.x;
  es[t] = e2s[(size_t)b * NN + t];
  es[t + 256] = e2s[(size_t)b * NN + t + 256];
  const unsigned* msrc = mask + (size_t)b * 16 * NN + d0;
  mw[t] = msrc[(t >> 5) * NN + (t & 31)];
  {
    int idx = t + 256;
    mw[idx] = msrc[(idx >> 5) * NN + (idx & 31)];
  }
  __syncthreads();
  int w = t >> 6, lane = t & 63, m = lane & 31, kg = lane >> 5;
  float ed = e2d[(size_t)b * NN + d0 + m];
  const short8* bfr = (const short8*)hb2 + (size_t)b * 32 * 2 * 64;
  f32x16 acc0, acc1;
#pragma unroll
  for (int q = 0; q < 16; ++q) { acc0[q] = 0.f; acc1[q] = 0.f; }
  float l = 0.f;
#pragma unroll
  for (int kk = 0; kk < 8; ++kk) {
    int kt = w * 8 + kk;
    unsigned wv = mw[(kt >> 1) * 32 + m];
    int shift = (kt & 1) * 16 + kg * 8;
    const float* ep = &es[kt * 16 + kg * 8];
    short8 a;
#pragma unroll
    for (int j = 0; j < 8; ++j) {
      float sc = ed + ep[j];
      sc = fmaxf(sc, NEG_SLOPE * sc);
      float pv = __expf(sc);
      pv = ((wv >> (shift + j)) & 1u) ? pv : 0.f;
      l += pv;
      a[j] = (short)f2bf(pv);
    }
    short8 bv0 = bfr[(kt * 2 + 0) * 64 + lane];
    short8 bv1 = bfr[(kt * 2 + 1) * 64 + lane];
    acc0 = __builtin_amdgcn_mfma_f32_32x32x16_bf16(a, bv0, acc0, 0, 0, 0);
    acc1 = __builtin_amdgcn_mfma_f32_32x32x16_bf16(a, bv1, acc1, 0, 0, 0);
  }
  lred[w][lane] = l;
#pragma unroll
  for (int reg = 0; reg < 16; ++reg) {
    cred[w][0][reg][lane] = acc0[reg];
    cred[w][1][reg][lane] = acc1[reg];
  }
  __syncthreads();
  if (t < 32) {
    float s = 0.f;
#pragma unroll
    for (int q = 0; q < 4; ++q) s += lred[q][t] + lred[q][t + 32];
    linv_s[t] = 1.f / s;
  }
  __syncthreads();
#pragma unroll
  for (int q = 0; q < 8; ++q) {
    int pos = t + q * 256;
    int nt = pos >> 10;
    int rem = pos & 1023;
    int reg = rem >> 6;
    int ln = rem & 63;
    float v = cred[0][nt][reg][ln] + cred[1][nt][reg][ln] +
              cred[2][nt][reg][ln] + cred[3][nt][reg][ln];
    int row = (reg & 3) + 8 * (reg >> 2) + 4 * (ln >> 5);
    int col = nt * 32 + (ln & 31);
    out[((size_t)b * NN + d0 + row) * 64 + col] = v * linv_s[row] + b2[col];
  }
}

extern "C" void kernel_launch(void* const* d_in, const int* in_sizes, int n_in,
                              void* d_out, int out_size, void* d_ws, size_t ws_size,
                              hipStream_t stream) {
  const float* x = (const float*)d_in[0];
  const int* adj = (const int*)d_in[1];
  const float* W1 = (const float*)d_in[2];
  const float* a1s = (const float*)d_in[3];
  const float* a1d = (const float*)d_in[4];
  const float* b1 = (const float*)d_in[5];
  const float* W2 = (const float*)d_in[6];
  const float* a2s = (const float*)d_in[7];
  const float* a2d = (const float*)d_in[8];
  const float* b2 = (const float*)d_in[9];
  float* out = (float*)d_out;

  char* w = (char*)d_ws;
  unsigned* mask = (unsigned*)w;                             // 1 MiB
  unsigned short* hb1 = (unsigned short*)(w + (4u << 20));   // 8 MiB
  float* e1s = (float*)(w + (12u << 20));                    // 256 KiB
  float* e1d = (float*)(w + (12u << 20) + (256u << 10));     // 256 KiB
  unsigned short* hb2 = (unsigned short*)(w + (21u << 20));  // 2 MiB
  float* e2s = (float*)(w + (23u << 20));                    // 64 KiB
  float* e2d = (float*)(w + (23u << 20) + (64u << 10));      // 64 KiB

  hipLaunchKernelGGL(k_g1m, dim3(512), dim3(256), 0, stream, adj, x, W1, a1s,
                     a1d, mask, hb1, e1s, e1d);
  hipLaunchKernelGGL(k_attn1g2, dim3(512), dim3(256), 0, stream, mask, hb1,
                     e1s, e1d, b1, W2, a2s, a2d, hb2, e2s, e2d);
  hipLaunchKernelGGL(k_attn2, dim3(512), dim3(256), 0, stream, mask, hb2, e2s,
                     e2d, b2, out);
}

// Round 6
// 123.134 us; speedup vs baseline: 1.1394x; 1.1394x over previous
//
#include <hip/hip_runtime.h>
#include <cstddef>

#define NN 512
#define NEG_SLOPE 0.2f

typedef __attribute__((ext_vector_type(8))) short short8;
typedef __attribute__((ext_vector_type(16))) float f32x16;

__device__ __forceinline__ unsigned short f2bf(float v) {
  unsigned u = __float_as_uint(v);
  return (unsigned short)((u + 0x7FFFu + ((u >> 16) & 1u)) >> 16);
}

// ---------------- K0: tiny weight prep. Blocks 0..7: W1 -> B-frags (8 n-tiles);
// blocks 8..15: W2 -> B-frags (2 n-tiles). No mask, no e-tiles.
__global__ __launch_bounds__(256) void k_prep(const float* __restrict__ W1,
                                              const float* __restrict__ W2,
                                              short8* __restrict__ W1B,
                                              short8* __restrict__ W2B) {
  int blk = blockIdx.x, t = threadIdx.x;
  if (blk < 8) {
    int idx = blk * 256 + t;  // 0..2047
    int unit = idx >> 6, lane = idx & 63;
    int nt = unit >> 2, kt = unit & 3;
    int f = nt * 32 + (lane & 31);
    int k0 = kt * 16 + ((lane >> 5) << 3);
    short8 r;
#pragma unroll
    for (int j = 0; j < 8; ++j) r[j] = (short)f2bf(W1[(k0 + j) * 256 + f]);
    W1B[idx] = r;
  } else {
    int idx = (blk - 8) * 256 + t;  // 0..2047
    int unit = idx >> 6, lane = idx & 63;
    int nt = unit >> 4, kt = unit & 15;
    int f = nt * 32 + (lane & 31);
    int k0 = kt * 16 + ((lane >> 5) << 3);
    short8 r;
#pragma unroll
    for (int j = 0; j < 8; ++j) r[j] = (short)f2bf(W2[(k0 + j) * 64 + f]);
    W2B[idx] = r;
  }
}

// ---------------- K1: fused mask-build + gemm1.
// Block (b,mt), 256 threads, no barriers. Waves 1..3 build the mask tile from adj
// (overlaps the 32MB adj scan with compute). Wave 0: coalesced W1B frags (dbuf),
// packs x in-register, 32 MFMAs, LDS-bounce to hb1 B-frags + fp32 e1 dots.
__global__ __launch_bounds__(256) void k_g1m(const int* __restrict__ adj,
                                             const float* __restrict__ x,
                                             const short8* __restrict__ W1B,
                                             const float* __restrict__ a1s,
                                             const float* __restrict__ a1d,
                                             unsigned* __restrict__ mask,
                                             unsigned short* __restrict__ hb1,
                                             float* __restrict__ e1s,
                                             float* __restrict__ e1d) {
  __shared__ float tile[32 * 36];  // stride 36: 16B-aligned rows for e-dot b128
  int i = blockIdx.x;
  int b = (i & 7) * 4 + ((i >> 3) & 3), mt = i >> 5;  // XCD-affine swizzle
  int d0 = mt * 32;
  int t = threadIdx.x;

  if (t >= 64) {
    // mask helper: 192 threads cover 512 (w,d) words
    int t2 = t - 64;
    const int* abase = adj + (size_t)b * NN * NN;
    for (int u = t2; u < 512; u += 192) {
      int d = d0 + (u & 31), w = u >> 5;
      unsigned wv = 0;
#pragma unroll
      for (int j = 0; j < 32; ++j) {
        int s = w * 32 + j;
        unsigned bit = ((abase[(size_t)s * NN + d] != 0) || (s == d)) ? 1u : 0u;
        wv |= bit << j;
      }
      mask[((size_t)b * 16 + w) * NN + d] = wv;
    }
    return;  // no barriers in this kernel
  }

  // ---- wave 0: gemm1
  int lane = t, m = lane & 31, kg = lane >> 5;
  const float* xrow = x + ((size_t)b * NN + d0 + m) * 64 + kg * 8;
  short8 a[4];
#pragma unroll
  for (int kt = 0; kt < 4; ++kt) {
    float4 v0 = *(const float4*)(xrow + kt * 16);
    float4 v1 = *(const float4*)(xrow + kt * 16 + 4);
    short8 r;
    r[0] = (short)f2bf(v0.x); r[1] = (short)f2bf(v0.y);
    r[2] = (short)f2bf(v0.z); r[3] = (short)f2bf(v0.w);
    r[4] = (short)f2bf(v1.x); r[5] = (short)f2bf(v1.y);
    r[6] = (short)f2bf(v1.z); r[7] = (short)f2bf(v1.w);
    a[kt] = r;
  }
  short8* hb8 = (short8*)hb1;
  // double-buffered coalesced W1B fragment loads
  short8 wf[2][4];
#pragma unroll
  for (int kt = 0; kt < 4; ++kt) wf[0][kt] = W1B[kt * 64 + lane];
  float e_h = 0.f;
#pragma unroll
  for (int nt = 0; nt < 8; ++nt) {
    int cur = nt & 1;
    if (nt < 7) {
#pragma unroll
      for (int kt = 0; kt < 4; ++kt)
        wf[cur ^ 1][kt] = W1B[((nt + 1) * 4 + kt) * 64 + lane];
    }
    f32x16 acc;
#pragma unroll
    for (int q = 0; q < 16; ++q) acc[q] = 0.f;
#pragma unroll
    for (int kt = 0; kt < 4; ++kt)
      acc = __builtin_amdgcn_mfma_f32_32x32x16_bf16(a[kt], wf[cur][kt], acc, 0, 0, 0);
#pragma unroll
    for (int reg = 0; reg < 16; ++reg) {
      int row = (reg & 3) + 8 * (reg >> 2) + 4 * kg;  // C/D row map (m74/m101)
      tile[row * 36 + m] = acc[reg];
    }
    // hb1 B-frag pack (intra-wave LDS RAW: compiler orders via lgkmcnt)
    int h = nt >> 1, ft = nt & 1;
#pragma unroll
    for (int ktl = 0; ktl < 2; ++ktl) {
      short8 r;
#pragma unroll
      for (int j = 0; j < 8; ++j)
        r[j] = (short)f2bf(tile[(ktl * 16 + kg * 8 + j) * 36 + m]);
      hb8[((((size_t)b * 4 + h) * 32 + mt * 2 + ktl) * 2 + ft) * 64 + lane] = r;
    }
    // fp32 e-dot on the tile: lane (row=m, which=kg)
    const float* coeff = (kg ? a1d : a1s) + h * 64 + ft * 32;
    float ep = 0.f;
#pragma unroll
    for (int c4 = 0; c4 < 8; ++c4) {
      float4 tv = *(const float4*)&tile[m * 36 + c4 * 4];
      float4 cv = *(const float4*)&coeff[c4 * 4];
      ep += tv.x * cv.x + tv.y * cv.y + tv.z * cv.z + tv.w * cv.w;
    }
    e_h += ep;
    if (ft) {
      float* p = kg ? e1d : e1s;
      p[((size_t)b * 4 + h) * NN + d0 + m] = e_h;
      e_h = 0.f;
    }
  }
}

// ---------------- K2: fused layer-1 attention + layer-2 GEMM (+e2 dots).
__global__ __launch_bounds__(256) void k_attn1g2(const unsigned* __restrict__ mask,
                                                 const unsigned short* __restrict__ hb1,
                                                 const float* __restrict__ e1s,
                                                 const float* __restrict__ e1d,
                                                 const float* __restrict__ b1,
                                                 const short8* __restrict__ W2B,
                                                 const float* __restrict__ a2s,
                                                 const float* __restrict__ a2d,
                                                 unsigned short* __restrict__ hb2,
                                                 float* __restrict__ e2s,
                                                 float* __restrict__ e2d) {
  __shared__ float es[4 * NN];             // 8 KB
  __shared__ unsigned mw[16 * 32];         // 2 KB
  __shared__ unsigned short ht[32 * 264];  // 16.5 KB
  __shared__ float tile2[2][32 * 36];      // 9.2 KB
  int i = blockIdx.x;
  int b = (i & 7) * 4 + ((i >> 3) & 3), mt = i >> 5;  // XCD-affine swizzle
  int d0 = mt * 32;
  int t = threadIdx.x;
  const float* esrc = e1s + (size_t)b * 4 * NN;
#pragma unroll
  for (int q = 0; q < 8; ++q) es[t + q * 256] = esrc[t + q * 256];
  const unsigned* msrc = mask + (size_t)b * 16 * NN + d0;
  mw[t] = msrc[(t >> 5) * NN + (t & 31)];
  {
    int idx = t + 256;
    mw[idx] = msrc[(idx >> 5) * NN + (idx & 31)];
  }
  __syncthreads();
  int h = t >> 6, lane = t & 63, m = lane & 31, kg = lane >> 5;
  float ed = e1d[((size_t)b * 4 + h) * NN + d0 + m];
  const short8* bfr = (const short8*)hb1 + ((size_t)b * 4 + h) * 32 * 2 * 64;
  f32x16 acc0, acc1;
#pragma unroll
  for (int q = 0; q < 16; ++q) { acc0[q] = 0.f; acc1[q] = 0.f; }
  float l = 0.f;
  for (int kt = 0; kt < 32; ++kt) {
    unsigned wv = mw[(kt >> 1) * 32 + m];
    int shift = (kt & 1) * 16 + kg * 8;
    const float* ep = &es[h * NN + kt * 16 + kg * 8];
    short8 a;
#pragma unroll
    for (int j = 0; j < 8; ++j) {
      float sc = ed + ep[j];
      sc = fmaxf(sc, NEG_SLOPE * sc);  // leaky_relu
      float pv = __expf(sc);           // scores O(+-8): no max-shift needed
      pv = ((wv >> (shift + j)) & 1u) ? pv : 0.f;
      l += pv;
      a[j] = (short)f2bf(pv);
    }
    short8 bv0 = bfr[(kt * 2 + 0) * 64 + lane];
    short8 bv1 = bfr[(kt * 2 + 1) * 64 + lane];
    acc0 = __builtin_amdgcn_mfma_f32_32x32x16_bf16(a, bv0, acc0, 0, 0, 0);
    acc1 = __builtin_amdgcn_mfma_f32_32x32x16_bf16(a, bv1, acc1, 0, 0, 0);
  }
  float lf = l + __shfl(l, lane ^ 32, 64);
  float linv = 1.f / lf;
  float bia0 = b1[h * 64 + m];
  float bia1 = b1[h * 64 + 32 + m];
#pragma unroll
  for (int reg = 0; reg < 16; ++reg) {
    int row = (reg & 3) + 8 * (reg >> 2) + 4 * kg;  // C/D row map
    float li = __shfl(linv, row, 64);
    float v0 = acc0[reg] * li + bia0;
    v0 = (v0 > 0.f) ? v0 : (__expf(v0) - 1.f);  // ELU
    float v1 = acc1[reg] * li + bia1;
    v1 = (v1 > 0.f) ? v1 : (__expf(v1) - 1.f);
    ht[row * 264 + h * 64 + m] = f2bf(v0);
    ht[row * 264 + h * 64 + 32 + m] = f2bf(v1);
  }
  __syncthreads();
  // ---- fused gemm2: waves 0/1 compute n-tile nt=w2 of h1a@W2 from ht
  int w2 = t >> 6;
  if (w2 < 2) {
    int nt = w2;
    short8 wfr[16];
#pragma unroll
    for (int kt = 0; kt < 16; ++kt) wfr[kt] = W2B[(nt * 16 + kt) * 64 + lane];
    f32x16 acc;
#pragma unroll
    for (int q = 0; q < 16; ++q) acc[q] = 0.f;
#pragma unroll
    for (int kt = 0; kt < 16; ++kt) {
      short8 av = *(const short8*)&ht[m * 264 + kt * 16 + kg * 8];
      acc = __builtin_amdgcn_mfma_f32_32x32x16_bf16(av, wfr[kt], acc, 0, 0, 0);
    }
    float* tw = tile2[nt];
#pragma unroll
    for (int reg = 0; reg < 16; ++reg) {
      int row = (reg & 3) + 8 * (reg >> 2) + 4 * kg;
      tw[row * 36 + m] = acc[reg];
    }
  }
  __syncthreads();
  if (w2 < 2) {
    // pack hb2 B-frags
    const float* tw = tile2[w2];
    short8* hb8 = (short8*)hb2;
#pragma unroll
    for (int ktl = 0; ktl < 2; ++ktl) {
      short8 r;
#pragma unroll
      for (int j = 0; j < 8; ++j)
        r[j] = (short)f2bf(tw[(ktl * 16 + kg * 8 + j) * 36 + m]);
      hb8[(((size_t)b * 32 + mt * 2 + ktl) * 2 + w2) * 64 + lane] = r;
    }
  } else {
    // waves 2/3: e2 dots. wave2 -> e2s, wave3 -> e2d
    const float* coeff = ((w2 == 2) ? a2s : a2d) + kg * 32;
    const float* tsrc = tile2[kg];
    float val = 0.f;
#pragma unroll
    for (int c4 = 0; c4 < 8; ++c4) {
      float4 tv = *(const float4*)&tsrc[m * 36 + c4 * 4];
      float4 cv = *(const float4*)&coeff[c4 * 4];
      val += tv.x * cv.x + tv.y * cv.y + tv.z * cv.z + tv.w * cv.w;
    }
    float tot = val + __shfl(val, lane ^ 32, 64);
    if (kg == 0) {
      float* p = (w2 == 2) ? e2s : e2d;
      p[(size_t)b * NN + d0 + m] = tot;
    }
  }
}

// ---------------- K3: layer-2 attention via MFMA, 4 waves split K, LDS reduce
__global__ __launch_bounds__(256) void k_attn2(const unsigned* __restrict__ mask,
                                               const unsigned short* __restrict__ hb2,
                                               const float* __restrict__ e2s,
                                               const float* __restrict__ e2d,
                                               const float* __restrict__ b2,
                                               float* __restrict__ out) {
  __shared__ float es[NN];
  __shared__ unsigned mw[16 * 32];
  __shared__ float cred[4][2][16][64];
  __shared__ float lred[4][64];
  __shared__ float linv_s[32];
  int i = blockIdx.x;
  int b = (i & 7) * 4 + ((i >> 3) & 3);  // XCD-affine swizzle
  int d0 = (i >> 5) * 32;
  int t = threadIdx.x;
  es[t] = e2s[(size_t)b * NN + t];
  es[t + 256] = e2s[(size_t)b * NN + t + 256];
  const unsigned* msrc = mask + (size_t)b * 16 * NN + d0;
  mw[t] = msrc[(t >> 5) * NN + (t & 31)];
  {
    int idx = t + 256;
    mw[idx] = msrc[(idx >> 5) * NN + (idx & 31)];
  }
  __syncthreads();
  int w = t >> 6, lane = t & 63, m = lane & 31, kg = lane >> 5;
  float ed = e2d[(size_t)b * NN + d0 + m];
  const short8* bfr = (const short8*)hb2 + (size_t)b * 32 * 2 * 64;
  f32x16 acc0, acc1;
#pragma unroll
  for (int q = 0; q < 16; ++q) { acc0[q] = 0.f; acc1[q] = 0.f; }
  float l = 0.f;
#pragma unroll
  for (int kk = 0; kk < 8; ++kk) {
    int kt = w * 8 + kk;
    unsigned wv = mw[(kt >> 1) * 32 + m];
    int shift = (kt & 1) * 16 + kg * 8;
    const float* ep = &es[kt * 16 + kg * 8];
    short8 a;
#pragma unroll
    for (int j = 0; j < 8; ++j) {
      float sc = ed + ep[j];
      sc = fmaxf(sc, NEG_SLOPE * sc);
      float pv = __expf(sc);
      pv = ((wv >> (shift + j)) & 1u) ? pv : 0.f;
      l += pv;
      a[j] = (short)f2bf(pv);
    }
    short8 bv0 = bfr[(kt * 2 + 0) * 64 + lane];
    short8 bv1 = bfr[(kt * 2 + 1) * 64 + lane];
    acc0 = __builtin_amdgcn_mfma_f32_32x32x16_bf16(a, bv0, acc0, 0, 0, 0);
    acc1 = __builtin_amdgcn_mfma_f32_32x32x16_bf16(a, bv1, acc1, 0, 0, 0);
  }
  lred[w][lane] = l;
#pragma unroll
  for (int reg = 0; reg < 16; ++reg) {
    cred[w][0][reg][lane] = acc0[reg];
    cred[w][1][reg][lane] = acc1[reg];
  }
  __syncthreads();
  if (t < 32) {
    float s = 0.f;
#pragma unroll
    for (int q = 0; q < 4; ++q) s += lred[q][t] + lred[q][t + 32];
    linv_s[t] = 1.f / s;
  }
  __syncthreads();
#pragma unroll
  for (int q = 0; q < 8; ++q) {
    int pos = t + q * 256;
    int nt = pos >> 10;
    int rem = pos & 1023;
    int reg = rem >> 6;
    int ln = rem & 63;
    float v = cred[0][nt][reg][ln] + cred[1][nt][reg][ln] +
              cred[2][nt][reg][ln] + cred[3][nt][reg][ln];
    int row = (reg & 3) + 8 * (reg >> 2) + 4 * (ln >> 5);
    int col = nt * 32 + (ln & 31);
    out[((size_t)b * NN + d0 + row) * 64 + col] = v * linv_s[row] + b2[col];
  }
}

extern "C" void kernel_launch(void* const* d_in, const int* in_sizes, int n_in,
                              void* d_out, int out_size, void* d_ws, size_t ws_size,
                              hipStream_t stream) {
  const float* x = (const float*)d_in[0];
  const int* adj = (const int*)d_in[1];
  const float* W1 = (const float*)d_in[2];
  const float* a1s = (const float*)d_in[3];
  const float* a1d = (const float*)d_in[4];
  const float* b1 = (const float*)d_in[5];
  const float* W2 = (const float*)d_in[6];
  const float* a2s = (const float*)d_in[7];
  const float* a2d = (const float*)d_in[8];
  const float* b2 = (const float*)d_in[9];
  float* out = (float*)d_out;

  char* w = (char*)d_ws;
  unsigned* mask = (unsigned*)w;                             // 1 MiB
  short8* W1B = (short8*)(w + (3u << 20));                   // 32 KiB
  short8* W2B = (short8*)(w + (3u << 20) + (64u << 10));     // 32 KiB
  unsigned short* hb1 = (unsigned short*)(w + (4u << 20));   // 8 MiB
  float* e1s = (float*)(w + (12u << 20));                    // 256 KiB
  float* e1d = (float*)(w + (12u << 20) + (256u << 10));     // 256 KiB
  unsigned short* hb2 = (unsigned short*)(w + (21u << 20));  // 2 MiB
  float* e2s = (float*)(w + (23u << 20));                    // 64 KiB
  float* e2d = (float*)(w + (23u << 20) + (64u << 10));      // 64 KiB

  hipLaunchKernelGGL(k_prep, dim3(16), dim3(256), 0, stream, W1, W2, W1B, W2B);
  hipLaunchKernelGGL(k_g1m, dim3(512), dim3(256), 0, stream, adj, x, W1B, a1s,
                     a1d, mask, hb1, e1s, e1d);
  hipLaunchKernelGGL(k_attn1g2, dim3(512), dim3(256), 0, stream, mask, hb1,
                     e1s, e1d, b1, W2B, a2s, a2d, hb2, e2s, e2d);
  hipLaunchKernelGGL(k_attn2, dim3(512), dim3(256), 0, stream, mask, hb2, e2s,
                     e2d, b2, out);
}